// Round 13
// baseline (338.011 us; speedup 1.0000x reference)
//
#include <hip/hip_runtime.h>
#include <hip/hip_bf16.h>
#include <stdint.h>

#define KTOT 8192
#define BM 64
#define BK 128
#define KSPLIT 4
#define KCHUNK (KTOT / KSPLIT)   // 2048
#define NIT (KCHUNK / BK)        // 16
#define TILE_BYTES (BM * BK * 2) // 16 KiB blocked-A tile image

typedef __attribute__((ext_vector_type(8))) __bf16 bf16x8;
typedef __attribute__((ext_vector_type(4))) float f32x4;

__device__ __forceinline__ unsigned short f2bf(float f) {
  union { float f; unsigned int u; } a;
  a.f = f;
  unsigned int r = (a.u + 0x7fffu + ((a.u >> 16) & 1u)) >> 16;
  return (unsigned short)r;
}

__device__ __forceinline__ uint2 pack4(f32x4 v) {
  union { unsigned short h[4]; uint2 u; } pk;
  pk.h[0] = f2bf(v[0]); pk.h[1] = f2bf(v[1]);
  pk.h[2] = f2bf(v[2]); pk.h[3] = f2bf(v[3]);
  return pk.u;
}

// Barrier that drains LDS only — global prefetches stay in flight (T4).
__device__ __forceinline__ void block_bar() {
  asm volatile("s_waitcnt lgkmcnt(0)" ::: "memory");
  __builtin_amdgcn_s_barrier();
  __builtin_amdgcn_sched_barrier(0);
}

// x [8192][64] f32  ->  xt [64][8192] bf16 (transposed)
__global__ __launch_bounds__(256) void xpose_f32_bf16(const float* __restrict__ x,
                                                      __hip_bfloat16* __restrict__ xt) {
  __shared__ unsigned short tile[64][72];
  const int r0 = blockIdx.x * 64;
  const int t = threadIdx.x;
  const int a = t >> 4;
  const int c4 = (t & 15) * 4;
#pragma unroll
  for (int rep = 0; rep < 4; ++rep) {
    int r = a + rep * 16;
    f32x4 v = __builtin_nontemporal_load(
        reinterpret_cast<const f32x4*>(x + (size_t)(r0 + r) * 64 + c4));
    tile[c4 + 0][r] = f2bf(v[0]);
    tile[c4 + 1][r] = f2bf(v[1]);
    tile[c4 + 2][r] = f2bf(v[2]);
    tile[c4 + 3][r] = f2bf(v[3]);
  }
  __syncthreads();
#pragma unroll
  for (int rep = 0; rep < 4; ++rep) {
    int j = a + rep * 16;
    uint2 v = *reinterpret_cast<const uint2*>(&tile[j][c4]);
    *reinterpret_cast<uint2*>((unsigned short*)xt + (size_t)j * KTOT + r0 + c4) = v;
  }
}

// R9 GEMM: part[kc][col][row] partials of C = A @ B, BT[128][8192] bf16.
template <int WBLK>
__global__ __launch_bounds__(512, 4) void gemm_part(
    const float* __restrict__ A, const __hip_bfloat16* __restrict__ BTv,
    float* __restrict__ part, unsigned char* __restrict__ ablk) {
  constexpr int SZ_A = BM * BK * 2;   // 16 KiB
  __shared__ __align__(16) unsigned char smem[2 * SZ_A];
  const unsigned short* BT = (const unsigned short*)BTv;

  const int bid = blockIdx.x;
  const int kc = (bid & 7) >> 1;                 // XCD-affine K-chunk
  const int mblk = ((bid >> 3) << 1) | (bid & 1);
  const int r0 = mblk * BM;
  const int kbase = kc * KCHUNK;
  const int it0 = mblk & (NIT - 1);              // K-phase rotation

  const int t = threadIdx.x;
  const int l = t & 63;
  const int w = t >> 6;

  const float* aptr[4];
  int loff[4];
#pragma unroll
  for (int r = 0; r < 4; ++r) {
    int idx = t + r * 512;
    int m = idx >> 5, c4 = idx & 31;
    aptr[r] = A + (size_t)(r0 + m) * KTOT + kbase + c4 * 4;
    loff[r] = m * 256 + ((c4 * 8) ^ ((m & 7) << 4));
  }
  unsigned char* tb0 =
      WBLK ? ablk + (size_t)(mblk * KSPLIT + kc) * NIT * TILE_BYTES : nullptr;

  const int lr = l & 15;
  const int g = l >> 4;
  const int col = w * 16 + lr;
  const unsigned short* bptr = BT + (size_t)col * KTOT + kbase + g * 8;
  const int asw = (lr & 7) << 4;

  f32x4 acc[4];
  const f32x4 fzero = {0.f, 0.f, 0.f, 0.f};
#pragma unroll
  for (int mt = 0; mt < 4; ++mt) acc[mt] = fzero;

  f32x4 av0[4], av1[4];
  bf16x8 Bf0[4], Bf1[4];
  unsigned char* lds0 = smem;
  unsigned char* lds1 = smem + SZ_A;

  auto kof = [&](int s) { return ((s + it0) & (NIT - 1)) * BK; };

#define LOAD_A(AV, K0)                                                        \
  _Pragma("unroll") for (int r = 0; r < 4; ++r)                               \
      AV[r] = __builtin_nontemporal_load(                                     \
          reinterpret_cast<const f32x4*>(aptr[r] + (K0)));
#define LOAD_B(BF, K0)                                                        \
  _Pragma("unroll") for (int ks = 0; ks < 4; ++ks)                            \
      BF[ks] = *reinterpret_cast<const bf16x8*>(bptr + (K0) + ks * 32);
#define WRITE_A(LDS, AV, RS)                                                  \
  _Pragma("unroll") for (int r = 0; r < 4; ++r) {                             \
    uint2 pk_ = pack4(AV[r]);                                                 \
    *reinterpret_cast<uint2*>((LDS) + loff[r]) = pk_;                         \
    if constexpr (WBLK)                                                       \
      *reinterpret_cast<uint2*>(tb0 + (size_t)(RS) * TILE_BYTES + loff[r]) =  \
          pk_;                                                                \
  }
#define COMPUTE(LDS, BF)                                                      \
  _Pragma("unroll") for (int ks = 0; ks < 4; ++ks) {                          \
    _Pragma("unroll") for (int mt = 0; mt < 4; ++mt) {                        \
      bf16x8 af_ = *reinterpret_cast<const bf16x8*>(                          \
          (LDS) + (mt * 16 + lr) * 256 + ((ks * 64 + g * 16) ^ asw));         \
      acc[mt] = __builtin_amdgcn_mfma_f32_16x16x32_bf16(af_, BF[ks], acc[mt], \
                                                        0, 0, 0);             \
    }                                                                         \
  }

  LOAD_A(av0, kof(0)); LOAD_B(Bf0, kof(0));
  LOAD_A(av1, kof(1)); LOAD_B(Bf1, kof(1));
  WRITE_A(lds0, av0, it0);
  block_bar();

#pragma unroll 1
  for (int s = 0; s < NIT; s += 2) {
    if (s + 1 < NIT) { WRITE_A(lds1, av1, (s + 1 + it0) & (NIT - 1)); }
    if (s + 2 < NIT) { LOAD_A(av0, kof(s + 2)); }
    COMPUTE(lds0, Bf0);
    if (s + 2 < NIT) { LOAD_B(Bf0, kof(s + 2)); }
    if (s + 1 < NIT) block_bar();
    if (s + 1 < NIT) {
      if (s + 2 < NIT) { WRITE_A(lds0, av0, (s + 2 + it0) & (NIT - 1)); }
      if (s + 3 < NIT) { LOAD_A(av1, kof(s + 3)); }
      COMPUTE(lds1, Bf1);
      if (s + 3 < NIT) { LOAD_B(Bf1, kof(s + 3)); }
      if (s + 2 < NIT) block_bar();
    }
  }

  float* pp = part + (size_t)(kc * 128 + col) * KTOT + r0 + g * 4;
#pragma unroll
  for (int mt = 0; mt < 4; ++mt)
    __builtin_nontemporal_store(acc[mt], reinterpret_cast<f32x4*>(pp + mt * 16));
#undef LOAD_A
#undef WRITE_A
}

// G3 variant: A from blocked bf16 tile images (dense 256 KB slabs per block).
__global__ __launch_bounds__(512, 4) void gemm_blocked(
    const unsigned char* __restrict__ ablk, const __hip_bfloat16* __restrict__ BTv,
    float* __restrict__ part) {
  constexpr int SZ_A = BM * BK * 2;
  __shared__ __align__(16) unsigned char smem[2 * SZ_A];
  const unsigned short* BT = (const unsigned short*)BTv;

  const int bid = blockIdx.x;
  const int kc = (bid & 7) >> 1;
  const int mblk = ((bid >> 3) << 1) | (bid & 1);
  const int r0 = mblk * BM;
  const int kbase = kc * KCHUNK;
  const int it0 = mblk & (NIT - 1);

  const int t = threadIdx.x;
  const int l = t & 63;
  const int w = t >> 6;

  int loff[4];
#pragma unroll
  for (int r = 0; r < 4; ++r) {
    int idx = t + r * 512;
    int m = idx >> 5, c4 = idx & 31;
    loff[r] = m * 256 + ((c4 * 8) ^ ((m & 7) << 4));
  }
  const unsigned char* tb0 =
      ablk + (size_t)(mblk * KSPLIT + kc) * NIT * TILE_BYTES;

  const int lr = l & 15;
  const int g = l >> 4;
  const int col = w * 16 + lr;
  const unsigned short* bptr = BT + (size_t)col * KTOT + kbase + g * 8;
  const int asw = (lr & 7) << 4;

  f32x4 acc[4];
  const f32x4 fzero = {0.f, 0.f, 0.f, 0.f};
#pragma unroll
  for (int mt = 0; mt < 4; ++mt) acc[mt] = fzero;

  uint2 bv0[4], bv1[4];
  bf16x8 Bf0[4], Bf1[4];
  unsigned char* lds0 = smem;
  unsigned char* lds1 = smem + SZ_A;

  auto kof = [&](int s) { return ((s + it0) & (NIT - 1)) * BK; };
  auto rs = [&](int s) { return (s + it0) & (NIT - 1); };

#define LOAD_A(BV, RS)                                                        \
  _Pragma("unroll") for (int r = 0; r < 4; ++r)                               \
      BV[r] = *reinterpret_cast<const uint2*>(                                \
          tb0 + (size_t)(RS) * TILE_BYTES + loff[r]);
#define LOAD_B(BF, K0)                                                        \
  _Pragma("unroll") for (int ks = 0; ks < 4; ++ks)                            \
      BF[ks] = *reinterpret_cast<const bf16x8*>(bptr + (K0) + ks * 32);
#define WRITE_A(LDS, BV)                                                      \
  _Pragma("unroll") for (int r = 0; r < 4; ++r)                               \
      *reinterpret_cast<uint2*>((LDS) + loff[r]) = BV[r];
#define COMPUTE(LDS, BF)                                                      \
  _Pragma("unroll") for (int ks = 0; ks < 4; ++ks) {                          \
    _Pragma("unroll") for (int mt = 0; mt < 4; ++mt) {                        \
      bf16x8 af_ = *reinterpret_cast<const bf16x8*>(                          \
          (LDS) + (mt * 16 + lr) * 256 + ((ks * 64 + g * 16) ^ asw));         \
      acc[mt] = __builtin_amdgcn_mfma_f32_16x16x32_bf16(af_, BF[ks], acc[mt], \
                                                        0, 0, 0);             \
    }                                                                         \
  }

  LOAD_A(bv0, rs(0)); LOAD_B(Bf0, kof(0));
  LOAD_A(bv1, rs(1)); LOAD_B(Bf1, kof(1));
  WRITE_A(lds0, bv0);
  block_bar();

#pragma unroll 1
  for (int s = 0; s < NIT; s += 2) {
    if (s + 1 < NIT) { WRITE_A(lds1, bv1); }
    if (s + 2 < NIT) { LOAD_A(bv0, rs(s + 2)); }
    COMPUTE(lds0, Bf0);
    if (s + 2 < NIT) { LOAD_B(Bf0, kof(s + 2)); }
    if (s + 1 < NIT) block_bar();
    if (s + 1 < NIT) {
      if (s + 2 < NIT) { WRITE_A(lds0, bv0); }
      if (s + 3 < NIT) { LOAD_A(bv1, rs(s + 3)); }
      COMPUTE(lds1, Bf1);
      if (s + 3 < NIT) { LOAD_B(Bf1, kof(s + 3)); }
      if (s + 2 < NIT) block_bar();
    }
  }

  float* pp = part + (size_t)(kc * 128 + col) * KTOT + r0 + g * 4;
#pragma unroll
  for (int mt = 0; mt < 4; ++mt)
    __builtin_nontemporal_store(acc[mt], reinterpret_cast<f32x4*>(pp + mt * 16));
#undef LOAD_A
#undef LOAD_B
#undef WRITE_A
#undef COMPUTE
}

// Combine KSPLIT partials + epilogue, separate halves (lo: cols 0-63, hi: 64-127).
__global__ __launch_bounds__(256) void reduce_sep(
    const float* __restrict__ part, float* __restrict__ out,
    const float* s_lo_p, const float* s_hi_p,
    const float* __restrict__ add_ptr, const float* add_s_p,
    __hip_bfloat16* bt_lo, __hip_bfloat16* bt_hi,
    int base_lo, int base_hi, int accum) {
  const int t = threadIdx.x;
  const int col = t & 127;
  const int rbase = blockIdx.x * 32 + (t >> 7) * 16;
  const float* p0 = part + (size_t)col * KTOT + rbase;
  const bool hi = col >= 64;
  const int col64 = hi ? col - 64 : col;
  __hip_bfloat16* bt = hi ? bt_hi : bt_lo;
  const int obase = hi ? base_hi : base_lo;
  const float s = hi ? (s_hi_p ? *s_hi_p : 0.f) : (s_lo_p ? *s_lo_p : 0.f);
  const float was = add_s_p ? *add_s_p : 0.f;
#pragma unroll
  for (int i = 0; i < 4; ++i) {
    f32x4 c = __builtin_nontemporal_load(
        reinterpret_cast<const f32x4*>(p0 + 4 * i));
#pragma unroll
    for (int k = 1; k < KSPLIT; ++k)
      c += __builtin_nontemporal_load(reinterpret_cast<const f32x4*>(
          p0 + (size_t)k * 128 * KTOT + 4 * i));
    if (bt)
      *reinterpret_cast<uint2*>((unsigned short*)bt + (size_t)col64 * KTOT + rbase + 4 * i) =
          pack4(c);
    if (obase >= 0) {
#pragma unroll
      for (int j = 0; j < 4; ++j) {
        int row = rbase + 4 * i + j;
        float v = s * c[j];
        if (add_ptr && !hi) v = fmaf(was, add_ptr[(size_t)row * 64 + col64], v);
        if (accum) v += out[(size_t)row * 128 + obase + col64];
        out[(size_t)row * 128 + obase + col64] = v;
      }
    }
  }
}

// Combine partials + cross-half epilogue: out[:,64+c] = sl*lo[c] + sh*hi[c];
// bt_lo = raw lo (bf16 transposed).
__global__ __launch_bounds__(256) void reduce_comb(
    const float* __restrict__ part, float* __restrict__ out,
    const float* s_lo_p, const float* s_hi_p, __hip_bfloat16* bt_lo) {
  const int t = threadIdx.x;
  const int c = t & 63;
  const int rbase = blockIdx.x * 32 + (t >> 6) * 8;
  const float* pl = part + (size_t)c * KTOT + rbase;
  const float* ph = part + (size_t)(c + 64) * KTOT + rbase;
  const float sl = *s_lo_p, sh = *s_hi_p;
#pragma unroll
  for (int i = 0; i < 2; ++i) {
    f32x4 lo = __builtin_nontemporal_load(reinterpret_cast<const f32x4*>(pl + 4 * i));
    f32x4 hv = __builtin_nontemporal_load(reinterpret_cast<const f32x4*>(ph + 4 * i));
#pragma unroll
    for (int k = 1; k < KSPLIT; ++k) {
      lo += __builtin_nontemporal_load(reinterpret_cast<const f32x4*>(
          pl + (size_t)k * 128 * KTOT + 4 * i));
      hv += __builtin_nontemporal_load(reinterpret_cast<const f32x4*>(
          ph + (size_t)k * 128 * KTOT + 4 * i));
    }
    *reinterpret_cast<uint2*>((unsigned short*)bt_lo + (size_t)c * KTOT + rbase + 4 * i) =
        pack4(lo);
#pragma unroll
    for (int j = 0; j < 4; ++j) {
      int row = rbase + 4 * i + j;
      out[(size_t)row * 128 + 64 + c] = sl * lo[j] + sh * hv[j];
    }
  }
}

// DIAGNOSTIC: plain sequential contiguous-slab read. Block b reads its own
// 512 KB slab of A_p, then of A_n (536 MB total). Template arg encodes the
// ws_size bucket (kernel name visible in rocprof): 3: >=160MiB, 2: >=96,
// 1: >=48, 0: less.
template <int WSB>
__global__ __launch_bounds__(512) void seq_read(
    const float* __restrict__ A0, const float* __restrict__ A1,
    float* __restrict__ sink) {
  const int b = blockIdx.x, t = threadIdx.x;
  const size_t base = (size_t)b * (1 << 17);   // 512 KB of floats per block
  f32x4 acc = {0.f, 0.f, 0.f, 0.f};
#pragma unroll 1
  for (int m = 0; m < 2; ++m) {
    const float* p = (m ? A1 : A0) + base + t * 4;
#pragma unroll 8
    for (int i = 0; i < 64; ++i)
      acc += *reinterpret_cast<const f32x4*>(p + (size_t)i * 2048);
  }
  sink[(size_t)b * 512 + t] = acc[0] + acc[1] + acc[2] + acc[3];
}

extern "C" void kernel_launch(void* const* d_in, const int* in_sizes, int n_in,
                              void* d_out, int out_size, void* d_ws, size_t ws_size,
                              hipStream_t stream) {
  const float* A_p = (const float*)d_in[0];
  const float* A_n = (const float*)d_in[1];
  const float* x_p = (const float*)d_in[2];
  const float* x_n = (const float*)d_in[3];
  const float* w_p = (const float*)d_in[4];  // [3]
  const float* w_n = (const float*)d_in[5];  // [3]
  float* out = (float*)d_out;                // [8192][128]

  __hip_bfloat16* BTbig = (__hip_bfloat16*)d_ws;
  __hip_bfloat16* B3T = BTbig + (size_t)192 * KTOT;
  float* part = (float*)(B3T + (size_t)128 * KTOT);
  unsigned char* ablk = (unsigned char*)(part + (size_t)KSPLIT * 128 * KTOT);
  const size_t base_need = (size_t)192 * KTOT * 2 + (size_t)128 * KTOT * 2 +
                           (size_t)KSPLIT * 128 * KTOT * 4;
  const size_t blk_need = (size_t)KTOT * KTOT * 2;   // 128 MiB
  const bool use_blk = ws_size >= base_need + blk_need;

  xpose_f32_bf16<<<128, 256, 0, stream>>>(x_p, BTbig);
  xpose_f32_bf16<<<128, 256, 0, stream>>>(x_n, BTbig + (size_t)64 * KTOT);

  // G1: [P1|Y1] = A_p @ [x_p|x_n]  (+ emit blocked bf16 A_p if ws allows)
  if (use_blk)
    gemm_part<1><<<512, 512, 0, stream>>>(A_p, BTbig, part, ablk);
  else
    gemm_part<0><<<512, 512, 0, stream>>>(A_p, BTbig, part, nullptr);
  reduce_sep<<<256, 256, 0, stream>>>(part, out, w_p + 1, nullptr, x_p, w_p + 0,
                                      B3T, BTbig + (size_t)128 * KTOT, 0, -1, 0);

  // G2': [T1|T3] = A_n @ [x_n|Y1]
  gemm_part<0><<<512, 512, 0, stream>>>(A_n, BTbig + (size_t)64 * KTOT, part,
                                        nullptr);
  reduce_comb<<<256, 256, 0, stream>>>(part, out, w_n + 0, w_n + 2,
                                       B3T + (size_t)64 * KTOT);

  // G3: [P2|T2] = A_p @ [P1|T1]
  if (use_blk)
    gemm_blocked<<<512, 512, 0, stream>>>(ablk, B3T, part);
  else
    gemm_part<0><<<512, 512, 0, stream>>>(A_p, B3T, part, nullptr);
  reduce_sep<<<256, 256, 0, stream>>>(part, out, w_p + 2, w_n + 1, nullptr, nullptr,
                                      nullptr, nullptr, 0, 64, 1);

  // DIAGNOSTIC (timed, additive): contiguous-slab read BW + ws_size bucket
  // encoded in the kernel-name template arg.
  if (ws_size >= base_need + blk_need)
    seq_read<3><<<512, 512, 0, stream>>>(A_p, A_n, part);
  else if (ws_size >= (size_t)96 << 20)
    seq_read<2><<<512, 512, 0, stream>>>(A_p, A_n, part);
  else if (ws_size >= (size_t)48 << 20)
    seq_read<1><<<512, 512, 0, stream>>>(A_p, A_n, part);
  else
    seq_read<0><<<512, 512, 0, stream>>>(A_p, A_n, part);
}

// Round 14
// 278.457 us; speedup vs baseline: 1.2139x; 1.2139x over previous
//
#include <hip/hip_runtime.h>
#include <hip/hip_bf16.h>
#include <stdint.h>

#define KTOT 8192
#define BM 64
#define BK 128
#define KSPLIT 4
#define KCHUNK (KTOT / KSPLIT)   // 2048
#define SK 256                   // staging window: 2 compute tiles, 1KB/row f32
#define NST (KCHUNK / SK)        // 8 staging steps
#define SZ_BUF (2 * BM * BK * 2) // 32 KiB per staging buffer (2 tiles)

typedef __attribute__((ext_vector_type(8))) __bf16 bf16x8;
typedef __attribute__((ext_vector_type(4))) float f32x4;

__device__ __forceinline__ unsigned short f2bf(float f) {
  union { float f; unsigned int u; } a;
  a.f = f;
  unsigned int r = (a.u + 0x7fffu + ((a.u >> 16) & 1u)) >> 16;
  return (unsigned short)r;
}

__device__ __forceinline__ uint2 pack4(f32x4 v) {
  union { unsigned short h[4]; uint2 u; } pk;
  pk.h[0] = f2bf(v[0]); pk.h[1] = f2bf(v[1]);
  pk.h[2] = f2bf(v[2]); pk.h[3] = f2bf(v[3]);
  return pk.u;
}

// Barrier that drains LDS only — global prefetches stay in flight (T4).
__device__ __forceinline__ void block_bar() {
  asm volatile("s_waitcnt lgkmcnt(0)" ::: "memory");
  __builtin_amdgcn_s_barrier();
  __builtin_amdgcn_sched_barrier(0);
}

// x [8192][64] f32  ->  xt [64][8192] bf16 (transposed)
__global__ __launch_bounds__(256) void xpose_f32_bf16(const float* __restrict__ x,
                                                      __hip_bfloat16* __restrict__ xt) {
  __shared__ unsigned short tile[64][72];
  const int r0 = blockIdx.x * 64;
  const int t = threadIdx.x;
  const int a = t >> 4;
  const int c4 = (t & 15) * 4;
#pragma unroll
  for (int rep = 0; rep < 4; ++rep) {
    int r = a + rep * 16;
    f32x4 v = __builtin_nontemporal_load(
        reinterpret_cast<const f32x4*>(x + (size_t)(r0 + r) * 64 + c4));
    tile[c4 + 0][r] = f2bf(v[0]);
    tile[c4 + 1][r] = f2bf(v[1]);
    tile[c4 + 2][r] = f2bf(v[2]);
    tile[c4 + 3][r] = f2bf(v[3]);
  }
  __syncthreads();
#pragma unroll
  for (int rep = 0; rep < 4; ++rep) {
    int j = a + rep * 16;
    uint2 v = *reinterpret_cast<const uint2*>(&tile[j][c4]);
    *reinterpret_cast<uint2*>((unsigned short*)xt + (size_t)j * KTOT + r0 + c4) = v;
  }
}

// part[kc][col][row] (f32, [KSPLIT][128][8192]) = raw C partials of
// C = A(f32 [8192][8192]) @ B, B transposed bf16 BT[128][8192].
// A staged in SK=256 windows: EACH WAVE INSTRUCTION READS ONE ROW'S 1 KB
// CONTIGUOUS SPAN (64 lanes x 16B) — the measured 5.4 TB/s pattern.
// Lanes 0-31 -> LDS tile-even, 32-63 -> tile-odd; XOR swizzle matches the
// R9 compute path. lgkm-only barriers; K-rotation; B direct global->reg.
__global__ __launch_bounds__(512, 4) void gemm_part(
    const float* __restrict__ A, const __hip_bfloat16* __restrict__ BTv,
    float* __restrict__ part) {
  __shared__ __align__(16) unsigned char smem[2 * SZ_BUF];   // 64 KiB
  const unsigned short* BT = (const unsigned short*)BTv;

  const int bid = blockIdx.x;
  const int kc = (bid & 7) >> 1;                 // XCD-affine K-chunk
  const int mblk = ((bid >> 3) << 1) | (bid & 1);
  const int r0 = mblk * BM;
  const int kbase = kc * KCHUNK;
  const int it0 = mblk & (NST - 1);              // staging-step rotation

  const int t = threadIdx.x;
  const int l = t & 63;
  const int w = t >> 6;

  // ---- A staging: wave w stages rows w*8..w*8+7; instruction r reads row
  // w*8+r's [koff + l*4 .. +3] — 1 KB contiguous per wave instruction.
  const float* abase = A + (size_t)(r0 + w * 8) * KTOT + kbase + l * 4;
  // LDS dest: tile (l>>5), row w*8+r, byte ((l&31)*8) ^ (r<<4)   [r = row&7]
  int loff[8];
#pragma unroll
  for (int r = 0; r < 8; ++r)
    loff[r] = (l >> 5) * (BM * BK * 2) + (w * 8 + r) * 256 +
              (((l & 31) * 8) ^ (r << 4));

  // ---- compute roles ----
  const int lr = l & 15;
  const int g = l >> 4;
  const int col = w * 16 + lr;
  const unsigned short* bptr = BT + (size_t)col * KTOT + kbase + g * 8;
  const int asw = (lr & 7) << 4;

  f32x4 acc[4];
  const f32x4 fzero = {0.f, 0.f, 0.f, 0.f};
#pragma unroll
  for (int mt = 0; mt < 4; ++mt) acc[mt] = fzero;

  f32x4 av[8];
  bf16x8 Bf0[4], Bf1[4];

  auto koff = [&](int s) { return ((s + it0) & (NST - 1)) * SK; };

#define LOAD_A(K0)                                                            \
  _Pragma("unroll") for (int r = 0; r < 8; ++r)                               \
      av[r] = __builtin_nontemporal_load(reinterpret_cast<const f32x4*>(      \
          abase + (size_t)r * KTOT + (K0)));
#define WRITE_A(BUF)                                                          \
  _Pragma("unroll") for (int r = 0; r < 8; ++r)                               \
      *reinterpret_cast<uint2*>((BUF) + loff[r]) = pack4(av[r]);
#define LOAD_B(BF, K0)                                                        \
  _Pragma("unroll") for (int ks = 0; ks < 4; ++ks)                            \
      BF[ks] = *reinterpret_cast<const bf16x8*>(bptr + (K0) + ks * 32);
#define COMPUTE(TILE, BF)                                                     \
  _Pragma("unroll") for (int ks = 0; ks < 4; ++ks) {                          \
    _Pragma("unroll") for (int mt = 0; mt < 4; ++mt) {                        \
      bf16x8 af_ = *reinterpret_cast<const bf16x8*>(                          \
          (TILE) + (mt * 16 + lr) * 256 + ((ks * 64 + g * 16) ^ asw));        \
      acc[mt] = __builtin_amdgcn_mfma_f32_16x16x32_bf16(af_, BF[ks], acc[mt], \
                                                        0, 0, 0);             \
    }                                                                         \
  }

  // prologue: step 0's A in flight
  LOAD_A(koff(0));

#pragma unroll 1
  for (int s = 0; s < NST; ++s) {
    unsigned char* buf = smem + (s & 1) * SZ_BUF;
    WRITE_A(buf);                    // vmcnt wait for av inserted by compiler
    block_bar();                     // drains ds_writes; readers(s-1) done
    if (s + 1 < NST) { LOAD_A(koff(s + 1)); }   // overlaps with compute
    LOAD_B(Bf0, koff(s));
    COMPUTE(buf, Bf0);                           // tile even
    LOAD_B(Bf1, koff(s) + BK);
    COMPUTE(buf + BM * BK * 2, Bf1);             // tile odd
  }

  // raw partial store (non-temporal): part[kc*128+col][r0 + mt*16 + g*4 .. +3]
  float* pp = part + (size_t)(kc * 128 + col) * KTOT + r0 + g * 4;
#pragma unroll
  for (int mt = 0; mt < 4; ++mt)
    __builtin_nontemporal_store(acc[mt], reinterpret_cast<f32x4*>(pp + mt * 16));
#undef LOAD_A
#undef WRITE_A
#undef LOAD_B
#undef COMPUTE
}

// Combine KSPLIT partials + epilogue, separate halves (lo: cols 0-63, hi: 64-127).
__global__ __launch_bounds__(256) void reduce_sep(
    const float* __restrict__ part, float* __restrict__ out,
    const float* s_lo_p, const float* s_hi_p,
    const float* __restrict__ add_ptr, const float* add_s_p,
    __hip_bfloat16* bt_lo, __hip_bfloat16* bt_hi,
    int base_lo, int base_hi, int accum) {
  const int t = threadIdx.x;
  const int col = t & 127;
  const int rbase = blockIdx.x * 32 + (t >> 7) * 16;
  const float* p0 = part + (size_t)col * KTOT + rbase;
  const bool hi = col >= 64;
  const int col64 = hi ? col - 64 : col;
  __hip_bfloat16* bt = hi ? bt_hi : bt_lo;
  const int obase = hi ? base_hi : base_lo;
  const float s = hi ? (s_hi_p ? *s_hi_p : 0.f) : (s_lo_p ? *s_lo_p : 0.f);
  const float was = add_s_p ? *add_s_p : 0.f;
#pragma unroll
  for (int i = 0; i < 4; ++i) {
    f32x4 c = __builtin_nontemporal_load(
        reinterpret_cast<const f32x4*>(p0 + 4 * i));
#pragma unroll
    for (int k = 1; k < KSPLIT; ++k)
      c += __builtin_nontemporal_load(reinterpret_cast<const f32x4*>(
          p0 + (size_t)k * 128 * KTOT + 4 * i));
    if (bt)
      *reinterpret_cast<uint2*>((unsigned short*)bt + (size_t)col64 * KTOT + rbase + 4 * i) =
          pack4(c);
    if (obase >= 0) {
#pragma unroll
      for (int j = 0; j < 4; ++j) {
        int row = rbase + 4 * i + j;
        float v = s * c[j];
        if (add_ptr && !hi) v = fmaf(was, add_ptr[(size_t)row * 64 + col64], v);
        if (accum) v += out[(size_t)row * 128 + obase + col64];
        out[(size_t)row * 128 + obase + col64] = v;
      }
    }
  }
}

// Combine partials + cross-half epilogue: out[:,64+c] = sl*lo[c] + sh*hi[c];
// bt_lo = raw lo (bf16 transposed).
__global__ __launch_bounds__(256) void reduce_comb(
    const float* __restrict__ part, float* __restrict__ out,
    const float* s_lo_p, const float* s_hi_p, __hip_bfloat16* bt_lo) {
  const int t = threadIdx.x;
  const int c = t & 63;
  const int rbase = blockIdx.x * 32 + (t >> 6) * 8;
  const float* pl = part + (size_t)c * KTOT + rbase;
  const float* ph = part + (size_t)(c + 64) * KTOT + rbase;
  const float sl = *s_lo_p, sh = *s_hi_p;
#pragma unroll
  for (int i = 0; i < 2; ++i) {
    f32x4 lo = __builtin_nontemporal_load(reinterpret_cast<const f32x4*>(pl + 4 * i));
    f32x4 hv = __builtin_nontemporal_load(reinterpret_cast<const f32x4*>(ph + 4 * i));
#pragma unroll
    for (int k = 1; k < KSPLIT; ++k) {
      lo += __builtin_nontemporal_load(reinterpret_cast<const f32x4*>(
          pl + (size_t)k * 128 * KTOT + 4 * i));
      hv += __builtin_nontemporal_load(reinterpret_cast<const f32x4*>(
          ph + (size_t)k * 128 * KTOT + 4 * i));
    }
    *reinterpret_cast<uint2*>((unsigned short*)bt_lo + (size_t)c * KTOT + rbase + 4 * i) =
        pack4(lo);
#pragma unroll
    for (int j = 0; j < 4; ++j) {
      int row = rbase + 4 * i + j;
      out[(size_t)row * 128 + 64 + c] = sl * lo[j] + sh * hv[j];
    }
  }
}

extern "C" void kernel_launch(void* const* d_in, const int* in_sizes, int n_in,
                              void* d_out, int out_size, void* d_ws, size_t ws_size,
                              hipStream_t stream) {
  const float* A_p = (const float*)d_in[0];
  const float* A_n = (const float*)d_in[1];
  const float* x_p = (const float*)d_in[2];
  const float* x_n = (const float*)d_in[3];
  const float* w_p = (const float*)d_in[4];  // [3]
  const float* w_n = (const float*)d_in[5];  // [3]
  float* out = (float*)d_out;                // [8192][128]

  // ws layout (21 MiB):
  //   BTbig [192][8192] bf16: rows 0-63 x_p^T, 64-127 x_n^T, 128-191 Y1^T
  //   B3T   [128][8192] bf16: rows 0-63 P1^T, 64-127 T1^T
  //   part  [KSPLIT][128][8192] f32
  __hip_bfloat16* BTbig = (__hip_bfloat16*)d_ws;
  __hip_bfloat16* B3T = BTbig + (size_t)192 * KTOT;
  float* part = (float*)(B3T + (size_t)128 * KTOT);

  xpose_f32_bf16<<<128, 256, 0, stream>>>(x_p, BTbig);
  xpose_f32_bf16<<<128, 256, 0, stream>>>(x_n, BTbig + (size_t)64 * KTOT);

  // G1: [P1|Y1] = A_p @ [x_p|x_n]
  gemm_part<<<512, 512, 0, stream>>>(A_p, BTbig, part);
  // out[:,0:64] = wp0*x_p + wp1*P1; emit P1^T -> B3T[0:64], Y1^T -> BTbig[128:192]
  reduce_sep<<<256, 256, 0, stream>>>(part, out, w_p + 1, nullptr, x_p, w_p + 0,
                                      B3T, BTbig + (size_t)128 * KTOT, 0, -1, 0);

  // G2': [T1|T3] = A_n @ [x_n|Y1]
  gemm_part<<<512, 512, 0, stream>>>(A_n, BTbig + (size_t)64 * KTOT, part);
  // out[:,64:128] = wn0*T1 + wn2*T3; emit T1^T -> B3T[64:128]
  reduce_comb<<<256, 256, 0, stream>>>(part, out, w_n + 0, w_n + 2,
                                       B3T + (size_t)64 * KTOT);

  // G3: [P2|T2] = A_p @ [P1|T1]
  gemm_part<<<512, 512, 0, stream>>>(A_p, B3T, part);
  // out[:,0:64] += wp2*P2; out[:,64:128] += wn1*T2
  reduce_sep<<<256, 256, 0, stream>>>(part, out, w_p + 2, w_n + 1, nullptr, nullptr,
                                      nullptr, nullptr, 0, 64, 1);
}